// Round 1
// baseline (185.914 us; speedup 1.0000x reference)
//
#include <hip/hip_runtime.h>
#include <math.h>

#define EPSF 1e-8f

// ws float layout:
// [0..15]  cnt per b (as int)
// [16] score_num  [17] score_cnt
// [18] gb_sum  [19] gi_sum  [20] gpa_sum
// [21] match1  [22] match2  [23] pose1  [24] pose2  [25] gpo

__device__ __forceinline__ float blockReduceSum(float v, float* sbuf) {
    int lane = threadIdx.x & 63;
    int wid  = threadIdx.x >> 6;
    #pragma unroll
    for (int o = 32; o > 0; o >>= 1) v += __shfl_down(v, o, 64);
    if (lane == 0) sbuf[wid] = v;
    __syncthreads();
    int nw = (blockDim.x + 63) >> 6;
    v = (wid == 0 && lane < nw) ? sbuf[lane] : 0.0f;
    if (wid == 0) {
        #pragma unroll
        for (int o = 32; o > 0; o >>= 1) v += __shfl_down(v, o, 64);
    }
    __syncthreads();   // safe for buffer reuse
    return v;          // valid in thread 0
}

// ---------------- K1: relation -> cnt[b] ----------------
__global__ void cnt_kernel(const float* __restrict__ rel, int* __restrict__ cntb) {
    int b = blockIdx.x;          // 16
    int t = threadIdx.x;         // 256
    int c = 0;
    for (int n = t; n < 4096; n += 256) {
        float r0 = rel[(b * 4096 + n) * 4 + 2];
        float r1 = rel[(b * 4096 + n) * 4 + 3];
        c += (r0 > 0.0f && r1 > 0.0f) ? 1 : 0;
    }
    __shared__ int s[256];
    s[t] = c;
    __syncthreads();
    for (int o = 128; o > 0; o >>= 1) {
        if (t < o) s[t] += s[t + o];
        __syncthreads();
    }
    if (t == 0) cntb[b] = s[0];
}

// ---------------- K2: score loss partials ----------------
__global__ void score_kernel(const float* __restrict__ score,
                             const float* __restrict__ label,
                             float* __restrict__ acc) {
    const int TOT = 8 * 512 * 512;   // 2097152
    float num = 0.0f, cntf = 0.0f;
    for (int i = blockIdx.x * blockDim.x + threadIdx.x; i < TOT;
         i += gridDim.x * blockDim.x) {
        float2 l = ((const float2*)label)[i];
        float s0 = score[i];
        float s1 = score[i + TOT];
        if (s0 > 1e-8f) { float d = s0 - l.x; num += d * d; cntf += 1.0f; }
        if (s1 > 1e-8f) { float d = s1 - l.y; num += d * d; cntf += 1.0f; }
    }
    __shared__ float sbuf[16];
    float r = blockReduceSum(num, sbuf);
    if (threadIdx.x == 0) atomicAdd(&acc[16], r);
    r = blockReduceSum(cntf, sbuf);
    if (threadIdx.x == 0) atomicAdd(&acc[17], r);
}

// ---------------- K3: feature cosine losses (hot) ----------------
__global__ __launch_bounds__(1024)
void feat_kernel(const float* __restrict__ f0, const float* __restrict__ f1,
                 const float* __restrict__ f2, const float* __restrict__ f3,
                 const float* __restrict__ f4, const float* __restrict__ f5,
                 const int* __restrict__ cntb, float* __restrict__ acc) {
    int blk   = blockIdx.x;        // 512 = 16 b * 32 chunks
    int b     = blk >> 5;
    int chunk = blk & 31;
    int t  = threadIdx.x;
    int nl = t & 127;              // n-lane within chunk
    int cq = t >> 7;               // 0..7 c-group
    int n  = chunk * 128 + nl;

    unsigned base = ((unsigned)b * 256 + (unsigned)cq * 32) * 4096u + (unsigned)n;

    float d01 = 0, s0 = 0, s1 = 0;
    float d23 = 0, s2 = 0, s3 = 0;
    float d45 = 0, s4 = 0, s5 = 0;
    #pragma unroll 4
    for (int i = 0; i < 32; i++) {
        unsigned idx = base + (unsigned)i * 4096u;
        float a0 = f0[idx], a1 = f1[idx];
        float a2 = f2[idx], a3 = f3[idx];
        float a4 = f4[idx], a5 = f5[idx];
        d01 += a0 * a1; s0 += a0 * a0; s1 += a1 * a1;
        d23 += a2 * a3; s2 += a2 * a2; s3 += a3 * a3;
        d45 += a4 * a5; s4 += a4 * a4; s5 += a5 * a5;
    }

    __shared__ float sd[9][8][128];
    sd[0][cq][nl] = d01; sd[1][cq][nl] = s0; sd[2][cq][nl] = s1;
    sd[3][cq][nl] = d23; sd[4][cq][nl] = s2; sd[5][cq][nl] = s3;
    sd[6][cq][nl] = d45; sd[7][cq][nl] = s4; sd[8][cq][nl] = s5;
    __syncthreads();

    float v_gb = 0.0f, v_gi = 0.0f, v_gpa = 0.0f;
    if (cq == 0) {
        float q[9];
        #pragma unroll
        for (int qi = 0; qi < 9; qi++) {
            float s = 0.0f;
            #pragma unroll
            for (int k = 0; k < 8; k++) s += sd[qi][k][nl];
            q[qi] = s;
        }
        float c0 = 1.0f - q[0] / fmaxf(sqrtf(q[1]) * sqrtf(q[2]), EPSF);
        float c1 = 1.0f - q[3] / fmaxf(sqrtf(q[4]) * sqrtf(q[5]), EPSF);
        float c2 = 1.0f - q[6] / fmaxf(sqrtf(q[7]) * sqrtf(q[8]), EPSF);
        int   cb    = cntb[b];
        float denom = fmaxf((float)cb, 1.0f);
        if (n < cb) { v_gb = c0 / denom; v_gi = c1 / denom; }
        v_gpa = c2;
    }

    __shared__ float rbuf[16];
    float r;
    r = blockReduceSum(v_gb, rbuf);
    if (t == 0) atomicAdd(&acc[18], r);
    r = blockReduceSum(v_gi, rbuf);
    if (t == 0) atomicAdd(&acc[19], r);
    r = blockReduceSum(v_gpa, rbuf);
    if (t == 0) atomicAdd(&acc[20], r);
}

// ---------------- K4: sinkhorn/pose/gen_points ----------------
__global__ void small_kernel(const float* __restrict__ kp,
                             const float* __restrict__ pose,
                             const float* __restrict__ t1,
                             const float* __restrict__ proj1,
                             const float* __restrict__ t2,
                             const float* __restrict__ proj2,
                             const float* __restrict__ kgen,
                             float* __restrict__ acc) {
    int i = blockIdx.x * blockDim.x + threadIdx.x;   // 65536
    int b = i >> 12;
    int n = i & 4095;

    float m1 = 0, m2 = 0, p1 = 0, p2 = 0, g = 0;
    float4 k = ((const float4*)kp)[i];

    if (b < 8) {
        const float* P  = pose + b * 16;
        const float* T1 = t1 + b * 16;
        const float* T2 = t2 + b * 16;
        float ssq1 = 0, ssq2 = 0;
        #pragma unroll
        for (int r = 0; r < 3; r++) {
            float base3 = P[r*4+0]*k.x + P[r*4+1]*k.y + P[r*4+2]*k.z;
            float g1 = base3 + P[r*4+3];          // w = 1 (sinkhorn)
            float gw = base3 + P[r*4+3]*k.w;      // w = k.w (pose loss)
            float q1 = proj1[i*3 + r];
            float q2 = proj2[i*3 + r];
            float d1 = g1 - q1, d2 = g1 - q2;
            ssq1 += d1 * d1; ssq2 += d2 * d2;
            float pa = T1[r*4+0]*k.x + T1[r*4+1]*k.y + T1[r*4+2]*k.z + T1[r*4+3]*k.w;
            float pb = T2[r*4+0]*k.x + T2[r*4+1]*k.y + T2[r*4+2]*k.z + T2[r*4+3]*k.w;
            p1 += fabsf(pa - gw);
            p2 += fabsf(pb - gw);
        }
        m1 = sqrtf(ssq1);
        m2 = sqrtf(ssq2);
        // gen_points, first half: src = raw key_points[b], tgt = kg[8+b][:2]
        float s0 = P[0]*k.x + P[1]*k.y + P[2]*k.z + P[3]*k.w;
        float s1 = P[4]*k.x + P[5]*k.y + P[6]*k.z + P[7]*k.w;
        float2 tg = ((const float2*)kgen)[(8 + b) * 4096 + n];
        g = fabsf(s0 - tg.x) + fabsf(s1 - tg.y);
    } else {
        // gen_points, second half: src = [kgx,kgy,0,1], tgt = key_points[b][:2]
        int j = b - 8;
        const float* P = pose + j * 16;
        float2 kg = ((const float2*)kgen)[j * 4096 + n];
        float s0 = P[0]*kg.x + P[1]*kg.y + P[3];
        float s1 = P[4]*kg.x + P[5]*kg.y + P[7];
        g = fabsf(s0 - k.x) + fabsf(s1 - k.y);
    }

    __shared__ float sbuf[16];
    float r;
    r = blockReduceSum(m1, sbuf); if (threadIdx.x == 0) atomicAdd(&acc[21], r);
    r = blockReduceSum(m2, sbuf); if (threadIdx.x == 0) atomicAdd(&acc[22], r);
    r = blockReduceSum(p1, sbuf); if (threadIdx.x == 0) atomicAdd(&acc[23], r);
    r = blockReduceSum(p2, sbuf); if (threadIdx.x == 0) atomicAdd(&acc[24], r);
    r = blockReduceSum(g,  sbuf); if (threadIdx.x == 0) atomicAdd(&acc[25], r);
}

// ---------------- K5: tr losses + final combine ----------------
__global__ void combine_kernel(const float* __restrict__ pose,
                               const float* __restrict__ t1,
                               const float* __restrict__ t2,
                               const float* __restrict__ ws,
                               float* __restrict__ out) {
    int t = threadIdx.x;   // 64
    float dt1 = 0, dt2 = 0, r1 = 0, r2 = 0;
    if (t < 8) {
        float ap = acosf(fminf(fmaxf(pose[t*16], -1.0f), 1.0f));
        float a1 = acosf(fminf(fmaxf(t1[t*16],   -1.0f), 1.0f));
        float a2 = acosf(fminf(fmaxf(t2[t*16],   -1.0f), 1.0f));
        r1 = fabsf(a1 - ap);
        r2 = fabsf(a2 - ap);
        float s1 = 0, s2 = 0;
        #pragma unroll
        for (int r = 0; r < 3; r++) {
            float pv = pose[t*16 + r*4 + 3];
            float d1 = t1[t*16 + r*4 + 3] - pv;
            float d2 = t2[t*16 + r*4 + 3] - pv;
            s1 += d1 * d1;
            s2 += d2 * d2;
        }
        dt1 = sqrtf(s1);
        dt2 = sqrtf(s2);
    }
    #pragma unroll
    for (int o = 4; o > 0; o >>= 1) {
        dt1 += __shfl_down(dt1, o, 64);
        dt2 += __shfl_down(dt2, o, 64);
        r1  += __shfl_down(r1,  o, 64);
        r2  += __shfl_down(r2,  o, 64);
    }
    if (t == 0) {
        float l_tra1 = dt1 / 8.0f;
        float l_tra2 = dt2 / 8.0f;
        float l_rot1 = (r1 / 8.0f) / 3.1415f * 180.0f;
        float l_rot2 = (r2 / 8.0f) / 3.1415f * 180.0f;
        float cnt = (fminf(l_rot1, l_rot2) > 0.0f) ? 2.0f : 1.0f;

        float l_score = ws[16] / fmaxf(ws[17], 1.0f);
        float l_match = (ws[21] + ws[22]) / 32768.0f / cnt;
        float l_pose  = (ws[23] + ws[24]) / 98304.0f / cnt;
        float l_tra   = (l_tra1 + l_tra2) / cnt;
        float l_rot   = (l_rot1 + l_rot2) / cnt;
        float l_gb    = ws[18] / 16.0f;
        float l_gi    = ws[19] / 16.0f;
        float l_gpa   = ws[20] / 65536.0f;
        float l_gpo   = ws[25] / 131072.0f;

        out[0] = l_pose + l_score + l_match + l_tra + l_rot
               + l_gb + l_gi + l_gpa + l_gpo;
    }
}

extern "C" void kernel_launch(void* const* d_in, const int* in_sizes, int n_in,
                              void* d_out, int out_size, void* d_ws, size_t ws_size,
                              hipStream_t stream) {
    const float* score_bev   = (const float*)d_in[0];
    const float* label_score = (const float*)d_in[1];
    const float* key_points  = (const float*)d_in[2];
    const float* pose        = (const float*)d_in[3];
    // d_in[4] = batch_size (scalar int, fixed = 16)
    const float* t_orig      = (const float*)d_in[5];
    const float* proj_orig   = (const float*)d_in[6];
    const float* t_fus       = (const float*)d_in[7];
    const float* proj_fus    = (const float*)d_in[8];
    const float* f_pt        = (const float*)d_in[9];
    const float* f_pt_g      = (const float*)d_in[10];
    const float* f_pl        = (const float*)d_in[11];
    const float* f_pl_g      = (const float*)d_in[12];
    const float* f_kpt       = (const float*)d_in[13];
    const float* f_kpt_g     = (const float*)d_in[14];
    const float* relation    = (const float*)d_in[15];
    const float* kgen        = (const float*)d_in[16];

    float* ws   = (float*)d_ws;
    int*   cntb = (int*)d_ws;   // ws[0..15] reused as int counts
    float* out  = (float*)d_out;

    hipMemsetAsync(d_ws, 0, 26 * sizeof(float), stream);

    cnt_kernel  <<<16,   256, 0, stream>>>(relation, cntb);
    score_kernel<<<2048, 256, 0, stream>>>(score_bev, label_score, ws);
    feat_kernel <<<512, 1024, 0, stream>>>(f_pt, f_pt_g, f_pl, f_pl_g,
                                           f_kpt, f_kpt_g, cntb, ws);
    small_kernel<<<256,  256, 0, stream>>>(key_points, pose, t_orig, proj_orig,
                                           t_fus, proj_fus, kgen, ws);
    combine_kernel<<<1,   64, 0, stream>>>(pose, t_orig, t_fus, ws, out);
}

// Round 2
// 145.977 us; speedup vs baseline: 1.2736x; 1.2736x over previous
//
#include <hip/hip_runtime.h>
#include <math.h>

#define EPSF 1e-8f

// ws float layout:
// [0..15]  cnt per b (float)
// [16] score_num  [17] score_cnt
// [18] gb_sum  [19] gi_sum  [20] gpa_sum
// [21] match1  [22] match2  [23] pose1  [24] pose2  [25] gpo

#define FEAT_BLOCKS  512   // 16 b * 32 chunks (128 n each)
#define SCORE_BLOCKS 128
#define SMALL_BLOCKS 256
#define MEGA_BLOCKS  (FEAT_BLOCKS + SCORE_BLOCKS + SMALL_BLOCKS)

__device__ __forceinline__ float blockReduceSum(float v, float* sbuf) {
    int lane = threadIdx.x & 63;
    int wid  = threadIdx.x >> 6;
    #pragma unroll
    for (int o = 32; o > 0; o >>= 1) v += __shfl_down(v, o, 64);
    if (lane == 0) sbuf[wid] = v;
    __syncthreads();
    int nw = (blockDim.x + 63) >> 6;
    v = (wid == 0 && lane < nw) ? sbuf[lane] : 0.0f;
    if (wid == 0) {
        #pragma unroll
        for (int o = 32; o > 0; o >>= 1) v += __shfl_down(v, o, 64);
    }
    __syncthreads();
    return v;          // valid in thread 0
}

__device__ __forceinline__ void fma4(float4& a, const float4 x, const float4 y) {
    a.x += x.x * y.x; a.y += x.y * y.y; a.z += x.z * y.z; a.w += x.w * y.w;
}
__device__ __forceinline__ float getc(const float4 v, int c) {
    return c == 0 ? v.x : (c == 1 ? v.y : (c == 2 ? v.z : v.w));
}

// ---------------- K1: relation -> cnt[b] (float counts in ws[0..15]) --------
__global__ void cnt_kernel(const float* __restrict__ rel, float* __restrict__ cntf) {
    int i = blockIdx.x * 256 + threadIdx.x;         // 65536 = 16*4096
    float4 r = ((const float4*)rel)[i];             // [.,.,r20,r21] -> z,w
    float c = (r.z > 0.0f && r.w > 0.0f) ? 1.0f : 0.0f;
    __shared__ float sbuf[16];
    float tot = blockReduceSum(c, sbuf);
    if (threadIdx.x == 0) atomicAdd(&cntf[i >> 12], tot);  // b constant per block
}

// ---------------- K2: mega kernel (feat + score + small, role by blockIdx) --
__global__ __launch_bounds__(256)
void mega_kernel(const float* __restrict__ f0, const float* __restrict__ f1,
                 const float* __restrict__ f2, const float* __restrict__ f3,
                 const float* __restrict__ f4, const float* __restrict__ f5,
                 const float* __restrict__ score, const float* __restrict__ label,
                 const float* __restrict__ kp,   const float* __restrict__ pose,
                 const float* __restrict__ t1,   const float* __restrict__ proj1,
                 const float* __restrict__ t2,   const float* __restrict__ proj2,
                 const float* __restrict__ kgen, float* __restrict__ acc) {
    __shared__ float4 sd4[9][8][32];   // feat role cross-group partials (36.9 KB)
    __shared__ float  rbuf[16];
    const int blk = blockIdx.x;
    const int t   = threadIdx.x;

    if (blk < FEAT_BLOCKS) {
        // ---- feature cosine losses (the hot stream: 402 MB) ----
        const int b     = blk >> 5;        // 16
        const int chunk = blk & 31;        // 32 chunks of 128 n
        const int nl    = t & 31;          // float4 lane along n
        const int cq    = t >> 5;          // 0..7 channel-group (32 ch each)
        const int n4    = chunk * 32 + nl; // float4-group id in [0,1024)

        const float4* F0 = (const float4*)f0;
        const float4* F1 = (const float4*)f1;
        const float4* F2 = (const float4*)f2;
        const float4* F3 = (const float4*)f3;
        const float4* F4 = (const float4*)f4;
        const float4* F5 = (const float4*)f5;
        unsigned base = ((unsigned)(b * 256 + cq * 32)) * 1024u + (unsigned)n4;

        float4 d01 = {0,0,0,0}, s0 = {0,0,0,0}, s1 = {0,0,0,0};
        float4 d23 = {0,0,0,0}, s2 = {0,0,0,0}, s3 = {0,0,0,0};
        float4 d45 = {0,0,0,0}, s4 = {0,0,0,0}, s5 = {0,0,0,0};
        #pragma unroll 2
        for (int i = 0; i < 32; i++) {
            unsigned idx = base + (unsigned)i * 1024u;
            float4 a0 = F0[idx], a1 = F1[idx];
            float4 a2 = F2[idx], a3 = F3[idx];
            float4 a4 = F4[idx], a5 = F5[idx];
            fma4(d01, a0, a1); fma4(s0, a0, a0); fma4(s1, a1, a1);
            fma4(d23, a2, a3); fma4(s2, a2, a2); fma4(s3, a3, a3);
            fma4(d45, a4, a5); fma4(s4, a4, a4); fma4(s5, a5, a5);
        }

        sd4[0][cq][nl] = d01; sd4[1][cq][nl] = s0; sd4[2][cq][nl] = s1;
        sd4[3][cq][nl] = d23; sd4[4][cq][nl] = s2; sd4[5][cq][nl] = s3;
        sd4[6][cq][nl] = d45; sd4[7][cq][nl] = s4; sd4[8][cq][nl] = s5;
        __syncthreads();

        float v_gb = 0.0f, v_gi = 0.0f, v_gpa = 0.0f;
        if (cq == 0) {
            float4 q[9];
            #pragma unroll
            for (int qi = 0; qi < 9; qi++) {
                float4 s = sd4[qi][0][nl];
                #pragma unroll
                for (int k = 1; k < 8; k++) fma4(s, sd4[qi][k][nl], {1,1,1,1});
                q[qi] = s;
            }
            float cb    = acc[b];                  // cnt (float) from K1
            float denom = fmaxf(cb, 1.0f);
            int   cbi   = (int)cb;
            #pragma unroll
            for (int comp = 0; comp < 4; comp++) {
                float c0 = 1.0f - getc(q[0],comp) /
                           fmaxf(sqrtf(getc(q[1],comp)) * sqrtf(getc(q[2],comp)), EPSF);
                float c1 = 1.0f - getc(q[3],comp) /
                           fmaxf(sqrtf(getc(q[4],comp)) * sqrtf(getc(q[5],comp)), EPSF);
                float c2 = 1.0f - getc(q[6],comp) /
                           fmaxf(sqrtf(getc(q[7],comp)) * sqrtf(getc(q[8],comp)), EPSF);
                int n = n4 * 4 + comp;
                if (n < cbi) { v_gb += c0 / denom; v_gi += c1 / denom; }
                v_gpa += c2;
            }
        }
        float r;
        r = blockReduceSum(v_gb,  rbuf); if (t == 0) atomicAdd(&acc[18], r);
        r = blockReduceSum(v_gi,  rbuf); if (t == 0) atomicAdd(&acc[19], r);
        r = blockReduceSum(v_gpa, rbuf); if (t == 0) atomicAdd(&acc[20], r);

    } else if (blk < FEAT_BLOCKS + SCORE_BLOCKS) {
        // ---- score loss (34 MB stream) ----
        const int sb = blk - FEAT_BLOCKS;
        const int TOT4 = (8 * 512 * 512) / 4;      // 524288 float4 slots
        const float4* S = (const float4*)score;
        const float4* L = (const float4*)label;
        float num = 0.0f, cntv = 0.0f;
        for (int j = sb * 256 + t; j < TOT4; j += SCORE_BLOCKS * 256) {
            float4 sa = S[j];
            float4 sb4 = S[TOT4 + j];
            float4 la = L[2 * j];
            float4 lb = L[2 * j + 1];
            if (sa.x > 1e-8f) { float d = sa.x - la.x; num += d*d; cntv += 1.0f; }
            if (sb4.x > 1e-8f){ float d = sb4.x - la.y; num += d*d; cntv += 1.0f; }
            if (sa.y > 1e-8f) { float d = sa.y - la.z; num += d*d; cntv += 1.0f; }
            if (sb4.y > 1e-8f){ float d = sb4.y - la.w; num += d*d; cntv += 1.0f; }
            if (sa.z > 1e-8f) { float d = sa.z - lb.x; num += d*d; cntv += 1.0f; }
            if (sb4.z > 1e-8f){ float d = sb4.z - lb.y; num += d*d; cntv += 1.0f; }
            if (sa.w > 1e-8f) { float d = sa.w - lb.z; num += d*d; cntv += 1.0f; }
            if (sb4.w > 1e-8f){ float d = sb4.w - lb.w; num += d*d; cntv += 1.0f; }
        }
        float r;
        r = blockReduceSum(num,  rbuf); if (t == 0) atomicAdd(&acc[16], r);
        r = blockReduceSum(cntv, rbuf); if (t == 0) atomicAdd(&acc[17], r);

    } else {
        // ---- sinkhorn / pose / gen_points (≈7 MB) ----
        const int i = (blk - FEAT_BLOCKS - SCORE_BLOCKS) * 256 + t;  // 0..65535
        const int b = i >> 12;
        const int n = i & 4095;

        float m1 = 0, m2 = 0, p1 = 0, p2 = 0, g = 0;
        float4 k = ((const float4*)kp)[i];

        if (b < 8) {
            const float* P  = pose + b * 16;
            const float* T1 = t1 + b * 16;
            const float* T2 = t2 + b * 16;
            float ssq1 = 0, ssq2 = 0;
            #pragma unroll
            for (int r = 0; r < 3; r++) {
                float base3 = P[r*4+0]*k.x + P[r*4+1]*k.y + P[r*4+2]*k.z;
                float g1 = base3 + P[r*4+3];          // w = 1 (sinkhorn)
                float gw = base3 + P[r*4+3]*k.w;      // w = k.w (pose loss)
                float q1 = proj1[i*3 + r];
                float q2 = proj2[i*3 + r];
                float d1 = g1 - q1, d2 = g1 - q2;
                ssq1 += d1 * d1; ssq2 += d2 * d2;
                float pa = T1[r*4+0]*k.x + T1[r*4+1]*k.y + T1[r*4+2]*k.z + T1[r*4+3]*k.w;
                float pb = T2[r*4+0]*k.x + T2[r*4+1]*k.y + T2[r*4+2]*k.z + T2[r*4+3]*k.w;
                p1 += fabsf(pa - gw);
                p2 += fabsf(pb - gw);
            }
            m1 = sqrtf(ssq1);
            m2 = sqrtf(ssq2);
            float s0 = P[0]*k.x + P[1]*k.y + P[2]*k.z + P[3]*k.w;
            float s1 = P[4]*k.x + P[5]*k.y + P[6]*k.z + P[7]*k.w;
            float2 tg = ((const float2*)kgen)[(8 + b) * 4096 + n];
            g = fabsf(s0 - tg.x) + fabsf(s1 - tg.y);
        } else {
            int j = b - 8;
            const float* P = pose + j * 16;
            float2 kg = ((const float2*)kgen)[j * 4096 + n];
            float s0 = P[0]*kg.x + P[1]*kg.y + P[3];
            float s1 = P[4]*kg.x + P[5]*kg.y + P[7];
            g = fabsf(s0 - k.x) + fabsf(s1 - k.y);
        }
        float r;
        r = blockReduceSum(m1, rbuf); if (t == 0) atomicAdd(&acc[21], r);
        r = blockReduceSum(m2, rbuf); if (t == 0) atomicAdd(&acc[22], r);
        r = blockReduceSum(p1, rbuf); if (t == 0) atomicAdd(&acc[23], r);
        r = blockReduceSum(p2, rbuf); if (t == 0) atomicAdd(&acc[24], r);
        r = blockReduceSum(g,  rbuf); if (t == 0) atomicAdd(&acc[25], r);
    }
}

// ---------------- K3: tr losses + final combine ----------------
__global__ void combine_kernel(const float* __restrict__ pose,
                               const float* __restrict__ t1,
                               const float* __restrict__ t2,
                               const float* __restrict__ ws,
                               float* __restrict__ out) {
    int t = threadIdx.x;   // 64
    float dt1 = 0, dt2 = 0, r1 = 0, r2 = 0;
    if (t < 8) {
        float ap = acosf(fminf(fmaxf(pose[t*16], -1.0f), 1.0f));
        float a1 = acosf(fminf(fmaxf(t1[t*16],   -1.0f), 1.0f));
        float a2 = acosf(fminf(fmaxf(t2[t*16],   -1.0f), 1.0f));
        r1 = fabsf(a1 - ap);
        r2 = fabsf(a2 - ap);
        float s1 = 0, s2 = 0;
        #pragma unroll
        for (int r = 0; r < 3; r++) {
            float pv = pose[t*16 + r*4 + 3];
            float d1 = t1[t*16 + r*4 + 3] - pv;
            float d2 = t2[t*16 + r*4 + 3] - pv;
            s1 += d1 * d1;
            s2 += d2 * d2;
        }
        dt1 = sqrtf(s1);
        dt2 = sqrtf(s2);
    }
    #pragma unroll
    for (int o = 4; o > 0; o >>= 1) {
        dt1 += __shfl_down(dt1, o, 64);
        dt2 += __shfl_down(dt2, o, 64);
        r1  += __shfl_down(r1,  o, 64);
        r2  += __shfl_down(r2,  o, 64);
    }
    if (t == 0) {
        float l_tra1 = dt1 / 8.0f;
        float l_tra2 = dt2 / 8.0f;
        float l_rot1 = (r1 / 8.0f) / 3.1415f * 180.0f;
        float l_rot2 = (r2 / 8.0f) / 3.1415f * 180.0f;
        float cnt = (fminf(l_rot1, l_rot2) > 0.0f) ? 2.0f : 1.0f;

        float l_score = ws[16] / fmaxf(ws[17], 1.0f);
        float l_match = (ws[21] + ws[22]) / 32768.0f / cnt;
        float l_pose  = (ws[23] + ws[24]) / 98304.0f / cnt;
        float l_tra   = (l_tra1 + l_tra2) / cnt;
        float l_rot   = (l_rot1 + l_rot2) / cnt;
        float l_gb    = ws[18] / 16.0f;
        float l_gi    = ws[19] / 16.0f;
        float l_gpa   = ws[20] / 65536.0f;
        float l_gpo   = ws[25] / 131072.0f;

        out[0] = l_pose + l_score + l_match + l_tra + l_rot
               + l_gb + l_gi + l_gpa + l_gpo;
    }
}

extern "C" void kernel_launch(void* const* d_in, const int* in_sizes, int n_in,
                              void* d_out, int out_size, void* d_ws, size_t ws_size,
                              hipStream_t stream) {
    const float* score_bev   = (const float*)d_in[0];
    const float* label_score = (const float*)d_in[1];
    const float* key_points  = (const float*)d_in[2];
    const float* pose        = (const float*)d_in[3];
    // d_in[4] = batch_size (scalar, fixed = 16)
    const float* t_orig      = (const float*)d_in[5];
    const float* proj_orig   = (const float*)d_in[6];
    const float* t_fus       = (const float*)d_in[7];
    const float* proj_fus    = (const float*)d_in[8];
    const float* f_pt        = (const float*)d_in[9];
    const float* f_pt_g      = (const float*)d_in[10];
    const float* f_pl        = (const float*)d_in[11];
    const float* f_pl_g      = (const float*)d_in[12];
    const float* f_kpt       = (const float*)d_in[13];
    const float* f_kpt_g     = (const float*)d_in[14];
    const float* relation    = (const float*)d_in[15];
    const float* kgen        = (const float*)d_in[16];

    float* ws  = (float*)d_ws;
    float* out = (float*)d_out;

    hipMemsetAsync(d_ws, 0, 26 * sizeof(float), stream);

    cnt_kernel<<<256, 256, 0, stream>>>(relation, ws);
    mega_kernel<<<MEGA_BLOCKS, 256, 0, stream>>>(
        f_pt, f_pt_g, f_pl, f_pl_g, f_kpt, f_kpt_g,
        score_bev, label_score,
        key_points, pose, t_orig, proj_orig, t_fus, proj_fus, kgen, ws);
    combine_kernel<<<1, 64, 0, stream>>>(pose, t_orig, t_fus, ws, out);
}